// Round 3
// baseline (1782.562 us; speedup 1.0000x reference)
//
#include <hip/hip_runtime.h>
#include <hip/hip_bf16.h>
#include <cstdint>

#define DEV_INLINE __device__ __forceinline__

using u16 = unsigned short;
typedef __attribute__((ext_vector_type(8))) short bf8_t;   // 8 x bf16 (4 VGPR)
typedef __attribute__((ext_vector_type(4))) float f32x4;

constexpr int cB = 16, cM = 80, cRPI = 256;
constexpr int cN = cB * cM;        // 1280
constexpr int cR = cB * cRPI;      // 4096
constexpr int cDF = 12544, cREP = 1024, cEMB = 256, cHID = 512, cNH = 8, cL = 4;
constexpr int cRELC = 51;

DEV_INLINE u16 f2bf(float x) { return __builtin_bit_cast(u16, __float2bfloat16(x)); }
DEV_INLINE float bf2f(u16 u) { return __bfloat162float(__builtin_bit_cast(__hip_bfloat16, u)); }

DEV_INLINE float wave_max(float v) {
#pragma unroll
  for (int o = 32; o; o >>= 1) v = fmaxf(v, __shfl_xor(v, o));
  return v;
}
DEV_INLINE float wave_sum(float v) {
#pragma unroll
  for (int o = 32; o; o >>= 1) v += __shfl_xor(v, o);
  return v;
}

DEV_INLINE bf8_t cvt8(float4 a, float4 b) {
  bf8_t r;
  r[0] = (short)f2bf(a.x); r[1] = (short)f2bf(a.y);
  r[2] = (short)f2bf(a.z); r[3] = (short)f2bf(a.w);
  r[4] = (short)f2bf(b.x); r[5] = (short)f2bf(b.y);
  r[6] = (short)f2bf(b.z); r[7] = (short)f2bf(b.w);
  return r;
}

// XCD-bijective remap (m204): each XCD gets a contiguous chunk of linear ids.
DEV_INLINE void xcd_remap(int& bx, int& by) {
  const int gx = gridDim.x;
  const int nwg = gx * gridDim.y;
  const int id = blockIdx.x + gx * blockIdx.y;
  const int q = nwg >> 3, r = nwg & 7;
  const int x = id & 7, k = id >> 3;
  const int idp = (x < r) ? x * (q + 1) + k : r * (q + 1) + (x - r) * q + k;
  bx = idp % gx;
  by = idp / gx;
}

// =====================================================================
// bf16 MFMA GEMM: C(MxN) = A(MxK bf16,row) @ W(NxK)^T. W bf16 or fp32 (BF32).
// 256 thr = 4 waves. BF32 path: W staged fp32 into LDS with pair-XOR swizzle
// (rows are 128B => unswizzled would be 16-way bank conflict), cvt->bf16 at
// frag build. SPLIT: blockIdx.z K-chunks, fp32 partials to outF + z*Mr*ldc.
// resmode: 0 none, 1 res[r*resld+c], 2 res[(r>>8)*resld+c] (row-broadcast).
// =====================================================================
template <int BM, int BN, bool SPLIT, bool BF32>
__global__ __launch_bounds__(256) void gemm_h(
    const u16* __restrict__ A, int lda,
    const void* __restrict__ Bw_, int ldb,
    int Mr, int Nr, int Klen,
    float* __restrict__ outF, int ldc,
    u16* __restrict__ outH, int ldh,
    const float* __restrict__ bias,
    const float* __restrict__ res, int resld, int resmode,
    int relu)
{
  constexpr int MF = BM / 32, NF = BN / 32;
  constexpr int BES = BF32 ? 4 : 2;
  __shared__ u16 As[BM * 32];
  __shared__ char BsRaw[BN * 32 * BES];
  const float* Bf = (const float*)Bw_;
  const u16* Bh = (const u16*)Bw_;

  const int tid = threadIdx.x;
  const int wid = tid >> 6, lane = tid & 63;
  int bx, by;
  xcd_remap(bx, by);
  const int bm = by * BM, bn = bx * BN;
  const int wr = wid >> 1, wc = wid & 1;
  const int kbase = SPLIT ? blockIdx.z * Klen : 0;

  f32x4 acc[MF][NF] = {};

  constexpr int AISS = (BM * 4) / 256;       // bf16: 4 x 16B chunks per row
  constexpr int BISS = (BN * 2 * BES) / 256; // 16B chunks per row: 4 (bf16) / 8 (f32)

  const int nk = Klen >> 5;
  for (int ks = 0; ks < nk; ++ks) {
    const int k0 = kbase + (ks << 5);
#pragma unroll
    for (int i = 0; i < AISS; ++i) {
      const int c = i * 256 + tid;
      const int row = c >> 2, seg = c & 3;
      const u16* gp = A + (size_t)(bm + row) * lda + k0 + seg * 8;
      __builtin_amdgcn_global_load_lds(
          (const __attribute__((address_space(1))) void*)gp,
          (__attribute__((address_space(3))) void*)((char*)As + (size_t)(i * 256 + wid * 64) * 16),
          16, 0, 0);
    }
#pragma unroll
    for (int i = 0; i < BISS; ++i) {
      const int c = i * 256 + tid;
      const void* gp;
      int row;
      if (BF32) {
        row = c >> 3;
        const int seg = c & 7;
        const int p = seg >> 1, w8 = seg & 1;
        const int sseg = ((p ^ (row & 3)) << 1) | w8;   // pre-swizzled source
        int brow = bn + row; if (brow > Nr - 1) brow = Nr - 1;
        gp = Bf + (size_t)brow * ldb + k0 + sseg * 4;
      } else {
        row = c >> 2;
        const int seg = c & 3;
        int brow = bn + row; if (brow > Nr - 1) brow = Nr - 1;
        gp = Bh + (size_t)brow * ldb + k0 + seg * 8;
      }
      __builtin_amdgcn_global_load_lds(
          (const __attribute__((address_space(1))) void*)gp,
          (__attribute__((address_space(3))) void*)(BsRaw + (size_t)(i * 256 + wid * 64) * 16),
          16, 0, 0);
    }
    __syncthreads();

    bf8_t af[MF], bfr[NF];
#pragma unroll
    for (int m = 0; m < MF; ++m) {
      const int r = wr * (BM / 2) + m * 16 + (lane & 15);
      af[m] = *(const bf8_t*)&As[r * 32 + (lane >> 4) * 8];
    }
#pragma unroll
    for (int n = 0; n < NF; ++n) {
      const int r = wc * (BN / 2) + n * 16 + (lane & 15);
      if (BF32) {
        const int h = (lane >> 4) ^ (r & 3);            // undo pair swizzle
        const float4* p = (const float4*)(BsRaw + (size_t)r * 128 + h * 32);
        bfr[n] = cvt8(p[0], p[1]);
      } else {
        bfr[n] = *(const bf8_t*)(BsRaw + ((size_t)r * 32 + (lane >> 4) * 8) * 2);
      }
    }
#pragma unroll
    for (int m = 0; m < MF; ++m)
#pragma unroll
      for (int n = 0; n < NF; ++n)
        acc[m][n] = __builtin_amdgcn_mfma_f32_16x16x32_bf16(af[m], bfr[n], acc[m][n], 0, 0, 0);
    __syncthreads();
  }

  if (SPLIT) {
    float* po = outF + (size_t)blockIdx.z * Mr * ldc;
#pragma unroll
    for (int m = 0; m < MF; ++m)
#pragma unroll
      for (int n = 0; n < NF; ++n) {
        const int ccol = bn + wc * (BN / 2) + n * 16 + (lane & 15);
        if (ccol >= Nr) continue;
#pragma unroll
        for (int g = 0; g < 4; ++g) {
          const int r = bm + wr * (BM / 2) + m * 16 + (lane >> 4) * 4 + g;
          po[(size_t)r * ldc + ccol] = acc[m][n][g];
        }
      }
  } else {
#pragma unroll
    for (int m = 0; m < MF; ++m)
#pragma unroll
      for (int n = 0; n < NF; ++n) {
        const int ccol = bn + wc * (BN / 2) + n * 16 + (lane & 15);
        if (ccol >= Nr) continue;
        const float bv = bias ? bias[ccol] : 0.f;
#pragma unroll
        for (int g = 0; g < 4; ++g) {
          const int r = bm + wr * (BM / 2) + m * 16 + (lane >> 4) * 4 + g;
          float v = acc[m][n][g] + bv;
          if (resmode == 1) v += res[(size_t)r * resld + ccol];
          else if (resmode == 2) v += res[(size_t)(r >> 8) * resld + ccol];
          if (relu) v = fmaxf(v, 0.f);
          if (outF) outF[(size_t)r * ldc + ccol] = v;
          if (outH) outH[(size_t)r * ldh + ccol] = f2bf(v);
        }
      }
  }
}

template <int BM, int BN, bool BF32>
static void g16(hipStream_t s, const u16* A, int lda, const void* W, int ldb,
                int M, int N, int K, float* outF, int ldc, u16* outH, int ldh,
                const float* bias, const float* res, int resld, int resmode, int relu) {
  dim3 g((N + BN - 1) / BN, M / BM);
  gemm_h<BM, BN, false, BF32><<<g, 256, 0, s>>>(A, lda, W, ldb, M, N, K, outF, ldc, outH, ldh,
                                                bias, res, resld, resmode, relu);
}

// =====================================================================
// Fused GEMM(32 rows x full 512 cols) + bias + residual + LayerNorm.
// 512 thr = 8 waves, each wave owns 64 cols. A (bf16) staged once (XOR-
// swizzled 16B granules); W fp32 staged per k-step (pair-XOR swizzle).
// Outputs y fp32 (residual for next stage) + y bf16 (next GEMM input).
// =====================================================================
__global__ __launch_bounds__(512) void gemm512_ln(
    const u16* __restrict__ A,            // [M][512] bf16
    const float* __restrict__ W,          // [512][512] fp32
    const float* __restrict__ bias,
    const float* __restrict__ res,        // [M][512] fp32
    float* __restrict__ yF,               // [M][512] fp32
    u16* __restrict__ yH, int ldh,        // [M][ldh] bf16
    const float* __restrict__ lnS, const float* __restrict__ lnB)
{
  __shared__ u16 As[32 * 512];        // 32 KB
  __shared__ float Bs[512 * 32];      // 64 KB
  __shared__ float lsum[32][8];
  __shared__ float lsq[32][8];
  __shared__ float lstat[32][2];

  const int tid = threadIdx.x;
  const int wid = tid >> 6, lane = tid & 63;
  const int l15 = lane & 15, l4 = lane >> 4;
  const int bm = blockIdx.x * 32;

  // stage A once: granule g' = g ^ (row&7) (rows are 1KB => would be 16-way)
#pragma unroll
  for (int i = 0; i < 4; ++i) {
    const int c = i * 512 + tid;
    const int row = c >> 6, seg = c & 63;
    const int seg2 = seg ^ (row & 7);
    const u16* gp = A + (size_t)(bm + row) * 512 + seg2 * 8;
    __builtin_amdgcn_global_load_lds(
        (const __attribute__((address_space(1))) void*)gp,
        (__attribute__((address_space(3))) void*)((char*)As + (size_t)(i * 512 + wid * 64) * 16),
        16, 0, 0);
  }

  f32x4 acc[2][4] = {};
  for (int ks = 0; ks < 16; ++ks) {
#pragma unroll
    for (int i = 0; i < 8; ++i) {
      const int c = i * 512 + tid;
      const int row = c >> 3, seg = c & 7;
      const int p = seg >> 1, w8 = seg & 1;
      const int sseg = ((p ^ (row & 3)) << 1) | w8;
      const float* gp = W + (size_t)row * 512 + ks * 32 + sseg * 4;
      __builtin_amdgcn_global_load_lds(
          (const __attribute__((address_space(1))) void*)gp,
          (__attribute__((address_space(3))) void*)((char*)Bs + (size_t)(i * 512 + wid * 64) * 16),
          16, 0, 0);
    }
    __syncthreads();

    bf8_t af[2], bfr[4];
#pragma unroll
    for (int m = 0; m < 2; ++m) {
      const int r = m * 16 + l15;
      const int g = ks * 4 + l4;
      const int g2 = g ^ (r & 7);
      af[m] = *(const bf8_t*)((const char*)As + (size_t)r * 1024 + g2 * 16);
    }
#pragma unroll
    for (int n = 0; n < 4; ++n) {
      const int r = wid * 64 + n * 16 + l15;
      const int h = l4 ^ (r & 3);
      const float4* p = (const float4*)((const char*)Bs + (size_t)r * 128 + h * 32);
      bfr[n] = cvt8(p[0], p[1]);
    }
#pragma unroll
    for (int m = 0; m < 2; ++m)
#pragma unroll
      for (int n = 0; n < 4; ++n)
        acc[m][n] = __builtin_amdgcn_mfma_f32_16x16x32_bf16(af[m], bfr[n], acc[m][n], 0, 0, 0);
    __syncthreads();
  }

  // epilogue: bias + residual, per-row stats across 8 waves, LN, store
  int col[4]; float ls_[4], lb_[4], bi_[4];
#pragma unroll
  for (int n = 0; n < 4; ++n) {
    col[n] = wid * 64 + n * 16 + l15;
    ls_[n] = lnS[col[n]]; lb_[n] = lnB[col[n]]; bi_[n] = bias[col[n]];
  }
  float v[2][4][4];
#pragma unroll
  for (int m = 0; m < 2; ++m)
#pragma unroll
    for (int g = 0; g < 4; ++g) {
      const int R = bm + m * 16 + l4 * 4 + g;
      float s = 0.f, q = 0.f;
#pragma unroll
      for (int n = 0; n < 4; ++n) {
        const float t = acc[m][n][g] + bi_[n] + res[(size_t)R * 512 + col[n]];
        v[m][n][g] = t; s += t; q += t * t;
      }
#pragma unroll
      for (int mk = 1; mk < 16; mk <<= 1) { s += __shfl_xor(s, mk); q += __shfl_xor(q, mk); }
      if (l15 == 0) { const int rl = m * 16 + l4 * 4 + g; lsum[rl][wid] = s; lsq[rl][wid] = q; }
    }
  __syncthreads();
  if (tid < 32) {
    float s = 0.f, q = 0.f;
#pragma unroll
    for (int w2 = 0; w2 < 8; ++w2) { s += lsum[tid][w2]; q += lsq[tid][w2]; }
    const float mean = s * (1.f / 512.f);
    const float var = q * (1.f / 512.f) - mean * mean;
    lstat[tid][0] = mean;
    lstat[tid][1] = rsqrtf(var + 1e-5f);
  }
  __syncthreads();
#pragma unroll
  for (int m = 0; m < 2; ++m)
#pragma unroll
    for (int g = 0; g < 4; ++g) {
      const int rl = m * 16 + l4 * 4 + g;
      const int R = bm + rl;
      const float mean = lstat[rl][0], inv = lstat[rl][1];
#pragma unroll
      for (int n = 0; n < 4; ++n) {
        const float y = (v[m][n][g] - mean) * inv * ls_[n] + lb_[n];
        yF[(size_t)R * 512 + col[n]] = y;
        yH[(size_t)R * ldh + col[n]] = f2bf(y);
      }
    }
}

// ---------- fp32 fallback GEMM (tiny shapes) ----------
__global__ __launch_bounds__(256) void gemm_nt(
    const float* __restrict__ A, int lda,
    const float* __restrict__ Bw, int ldb,
    float* __restrict__ C, int ldc,
    const float* __restrict__ bias,
    int Mr, int Nr, int Kr, int flags)
{
  __shared__ float As[16][68];
  __shared__ float Bs[16][68];
  const int tid = threadIdx.x;
  const int tx = tid & 15, ty = tid >> 4;
  const int bm = blockIdx.y * 64, bn = blockIdx.x * 64;
  const int lr = tid >> 2;
  const int lk = (tid & 3) * 4;

  float acc[4][4];
#pragma unroll
  for (int i = 0; i < 4; ++i)
#pragma unroll
    for (int j = 0; j < 4; ++j) acc[i][j] = 0.f;

  for (int k0 = 0; k0 < Kr; k0 += 16) {
    const int ar = bm + lr, br = bn + lr;
#pragma unroll
    for (int j = 0; j < 4; ++j) {
      const int kk = k0 + lk + j;
      float va = 0.f, vb = 0.f;
      if (kk < Kr) {
        if (ar < Mr) va = A[(size_t)ar * lda + kk];
        if (br < Nr) vb = Bw[(size_t)br * ldb + kk];
      }
      As[lk + j][lr] = va;
      Bs[lk + j][lr] = vb;
    }
    __syncthreads();
#pragma unroll
    for (int kk = 0; kk < 16; ++kk) {
      const float a0 = As[kk][ty * 4 + 0], a1 = As[kk][ty * 4 + 1],
                  a2 = As[kk][ty * 4 + 2], a3 = As[kk][ty * 4 + 3];
      const float b0 = Bs[kk][tx * 4 + 0], b1 = Bs[kk][tx * 4 + 1],
                  b2 = Bs[kk][tx * 4 + 2], b3 = Bs[kk][tx * 4 + 3];
      acc[0][0] += a0 * b0; acc[0][1] += a0 * b1; acc[0][2] += a0 * b2; acc[0][3] += a0 * b3;
      acc[1][0] += a1 * b0; acc[1][1] += a1 * b1; acc[1][2] += a1 * b2; acc[1][3] += a1 * b3;
      acc[2][0] += a2 * b0; acc[2][1] += a2 * b1; acc[2][2] += a2 * b2; acc[2][3] += a2 * b3;
      acc[3][0] += a3 * b0; acc[3][1] += a3 * b1; acc[3][2] += a3 * b2; acc[3][3] += a3 * b3;
    }
    __syncthreads();
  }
#pragma unroll
  for (int i = 0; i < 4; ++i) {
    const int r = bm + ty * 4 + i;
    if (r >= Mr) continue;
#pragma unroll
    for (int j = 0; j < 4; ++j) {
      const int c = bn + tx * 4 + j;
      if (c >= Nr) continue;
      float v = acc[i][j];
      if (bias) v += bias[c];
      if (flags & 2) v = fmaxf(v, 0.f);
      C[(size_t)r * ldc + c] = v;
    }
  }
}

// ---------- small kernels ----------
__global__ void conv_kernel(const float* __restrict__ s, u16* __restrict__ d, int n4) {
  const int i = blockIdx.x * 256 + threadIdx.x;
  if (i >= n4) return;
  const float4 v = ((const float4*)s)[i];
  ushort4 o;
  o.x = f2bf(v.x); o.y = f2bf(v.y); o.z = f2bf(v.z); o.w = f2bf(v.w);
  ((ushort4*)d)[i] = o;
}

__global__ void conv2d_kernel(const float* __restrict__ src, int slda,
                              u16* __restrict__ dst, int dld, int cols) {
  const int r = blockIdx.x;
  for (int c = threadIdx.x; c < cols; c += blockDim.x)
    dst[(size_t)r * dld + c] = f2bf(src[(size_t)r * slda + c]);
}

__global__ void addb_kernel(const float* a, const float* b, float* o, int n) {
  const int i = threadIdx.x;
  if (i < n) o[i] = a[i] + b[i];
}

__global__ void box_info_kernel(const float* __restrict__ boxes, float* __restrict__ bi) {
  const int i = blockIdx.x * blockDim.x + threadIdx.x;
  if (i >= cN) return;
  const float x1 = boxes[i * 4 + 0], y1 = boxes[i * 4 + 1];
  const float x2 = boxes[i * 4 + 2], y2 = boxes[i * 4 + 3];
  const float w = x2 - x1 + 1.f, h = y2 - y1 + 1.f;
  const float cx = x1 + 0.5f * w, cy = y1 + 0.5f * h;
  float* o = bi + (size_t)i * 9;
  o[0] = w / 800.f;  o[1] = h / 600.f;
  o[2] = cx / 800.f; o[3] = cy / 600.f;
  o[4] = x1 / 800.f; o[5] = y1 / 600.f;
  o[6] = x2 / 800.f; o[7] = y2 / 600.f;
  o[8] = (w * h) / (800.f * 600.f);
}

__global__ void gather_emb_h(const float* __restrict__ emb, const int* __restrict__ labels,
                             u16* __restrict__ dst, int dld) {
  const int i = blockIdx.x;
  const int l = labels[i];
  const float* s = emb + (size_t)l * cEMB;
  for (int c = threadIdx.x; c < cEMB; c += blockDim.x)
    dst[(size_t)i * dld + c] = f2bf(s[c]);
}

// fused attention per (b,h): qkv bf16 in, bf16 out
__global__ __launch_bounds__(256) void attn_kernel(const u16* __restrict__ qkv,
                                                   u16* __restrict__ o) {
  __shared__ float Ks[80][65];
  __shared__ float Vs[80][65];
  const int bh = blockIdx.x;
  const int b = bh >> 3, h = bh & 7;
  const int tid = threadIdx.x;
  const u16* base = qkv + (size_t)(b * cM) * 1536 + h * 64;

  for (int e = tid; e < 80 * 64; e += 256) {
    const int r = e >> 6, d = e & 63;
    Ks[r][d] = bf2f(base[(size_t)r * 1536 + 512 + d]);
    Vs[r][d] = bf2f(base[(size_t)r * 1536 + 1024 + d]);
  }
  __syncthreads();

  const int wave = tid >> 6, lane = tid & 63;
  const int r0 = blockIdx.y * 16;
  for (int r = r0 + wave; r < r0 + 16; r += 4) {
    const float qd = bf2f(base[(size_t)r * 1536 + lane]);
    const int c2 = 64 + lane;
    const int c2c = (c2 < 80) ? c2 : 0;
    float s0 = 0.f, s1 = 0.f;
#pragma unroll 8
    for (int d = 0; d < 64; ++d) {
      const float qv = __shfl(qd, d);
      s0 += qv * Ks[lane][d];
      s1 += qv * Ks[c2c][d];
    }
    s0 *= 0.125f;
    s1 = (c2 < 80) ? s1 * 0.125f : -1e30f;
    const float mx = wave_max(fmaxf(s0, s1));
    const float p0 = __expf(s0 - mx);
    const float p1 = (c2 < 80) ? __expf(s1 - mx) : 0.f;
    const float ssum = wave_sum(p0 + p1);

    float od = 0.f;
#pragma unroll 8
    for (int c = 0; c < 64; ++c) od += __shfl(p0, c) * Vs[c][lane];
#pragma unroll
    for (int c = 0; c < 16; ++c) od += __shfl(p1, c) * Vs[64 + c][lane];
    od /= ssum;
    o[(size_t)(b * cM + r) * cHID + h * 64 + lane] = f2bf(od);
  }
}

__global__ void mean_kernel(const float* __restrict__ x, float* __restrict__ gctx) {
  const int b = blockIdx.x;
  const int c = threadIdx.x;  // 512
  float s = 0.f;
  for (int m = 0; m < cM; ++m) s += x[(size_t)(b * cM + m) * cHID + c];
  gctx[(size_t)b * cHID + c] = s * (1.f / 80.f);
}

__global__ void pair_gather_h(const u16* __restrict__ obj, int old, const int* __restrict__ idx,
                              u16* __restrict__ pair) {
  const int r = blockIdx.x;
  const int b = r >> 8, rr = r & 255;
  const int i0 = idx[(size_t)(b * cRPI + rr) * 2 + 0];
  const int i1 = idx[(size_t)(b * cRPI + rr) * 2 + 1];
  const u16* hsrc = obj + (size_t)(b * cM + i0) * old;
  const u16* tsrc = obj + (size_t)(b * cM + i1) * old;
  u16* p = pair + (size_t)r * 1024;
  for (int c = threadIdx.x; c < cHID; c += blockDim.x) {
    p[c] = hsrc[c];
    p[cHID + c] = tsrc[c];
  }
}

// fe1 split-K=8 reduce: +bias, relu -> bf16
__global__ void reduce8_kernel(const float* __restrict__ p, const float* __restrict__ bias,
                               u16* __restrict__ outH) {
  const int idx = blockIdx.x * 256 + threadIdx.x;
  constexpr int total = cN * cREP;
  if (idx >= total) return;
  float v = bias[idx & 1023];
#pragma unroll
  for (int z = 0; z < 8; ++z) v += p[(size_t)z * total + idx];
  outH[idx] = f2bf(fmaxf(v, 0.f));
}

// final split-K=4 reduce: +combined bias -> fp32 d_out
__global__ void freduce_kernel(const float* __restrict__ p, const float* __restrict__ biasc,
                               float* __restrict__ out) {
  const int idx = blockIdx.x * 256 + threadIdx.x;
  if (idx >= cR * cRELC) return;
  const int r = idx / cRELC, c = idx - r * cRELC;
  float v = biasc[c];
#pragma unroll
  for (int z = 0; z < 4; ++z) v += p[(size_t)z * cR * 64 + (size_t)r * 64 + c];
  out[idx] = v;
}

// ---------- encoder: 5 dispatches per layer ----------
static void run_encoder(hipStream_t s, float* x, u16* xh, u16* qkvh, u16* attn_h,
                        float* res1, u16* f_h,
                        const float* qkvw, const float* qkvb,
                        const float* outw, const float* outb,
                        const float* f1w, const float* f1b,
                        const float* f2w, const float* f2b,
                        const float* ln1s, const float* ln1b,
                        const float* ln2s, const float* ln2b,
                        u16* last_bf, int last_ld) {
  for (int l = 0; l < cL; ++l) {
    g16<64, 64, true>(s, xh, 512, qkvw + (size_t)l * 1536 * 512, 512, cN, 1536, 512,
                      nullptr, 0, qkvh, 1536, qkvb + l * 1536, nullptr, 0, 0, 0);
    attn_kernel<<<dim3(cB * cNH, 5), 256, 0, s>>>(qkvh, attn_h);
    gemm512_ln<<<cN / 32, 512, 0, s>>>(attn_h, outw + (size_t)l * 512 * 512, outb + l * 512,
                                       x, res1, xh, 512, ln1s + l * 512, ln1b + l * 512);
    g16<64, 64, true>(s, xh, 512, f1w + (size_t)l * 512 * 512, 512, cN, 512, 512,
                      nullptr, 0, f_h, 512, f1b + l * 512, nullptr, 0, 0, 1);
    const bool last = (l == cL - 1);
    gemm512_ln<<<cN / 32, 512, 0, s>>>(f_h, f2w + (size_t)l * 512 * 512, f2b + l * 512,
                                       res1, x, last ? last_bf : xh, last ? last_ld : 512,
                                       ln2s + l * 512, ln2b + l * 512);
  }
}

// ===== workspace layout (bytes) =====
// phase1: feat_h(0..32.1M) | fe1w_h(32.1..57.8M) | part(57.8..99.7M) — all dead after reduce8
// phase2 (overlays 0..52.3M): pair|finalb|obj_in|qkvh|x|xh|attn_h|res1|f_h|edge_in
// persistent from 99.7M.
constexpr size_t OFF_FEAT  = 0;
constexpr size_t OFF_FE1W  = 32112640;
constexpr size_t OFF_PART  = 57802752;   // 8*1280*1024*4 = 41,943,040
constexpr size_t P_END     = 99745792;
constexpr size_t OFF_PAIR  = 0;          //  8,388,608
constexpr size_t OFF_FINAL = 8388608;    // 25,165,824
constexpr size_t OFF_OBJIN = 33554432;   //  3,604,480
constexpr size_t OFF_QKVH  = 37158912;   //  3,932,160
constexpr size_t OFF_X     = 41091072;   //  2,621,440
constexpr size_t OFF_XH    = 43712512;   //  1,310,720
constexpr size_t OFF_ATTN  = 45023232;   //  1,310,720
constexpr size_t OFF_RES   = 46333952;   //  2,621,440
constexpr size_t OFF_FH    = 48955392;   //  1,310,720
constexpr size_t OFF_EDGE  = 50266112;   //  1,966,080 -> ends 52,232,192

extern "C" void kernel_launch(void* const* d_in, const int* in_sizes, int n_in,
                              void* d_out, int out_size, void* d_ws, size_t ws_size,
                              hipStream_t stream) {
  (void)in_sizes; (void)n_in; (void)out_size; (void)ws_size;

  const float* features = (const float*)d_in[0];
  const float* unionf   = (const float*)d_in[1];
  const float* boxes    = (const float*)d_in[2];
  const int*   labels   = (const int*)d_in[4];
  const int*   relidx   = (const int*)d_in[5];
  const float* fe1_w = (const float*)d_in[6];
  const float* fe1_b = (const float*)d_in[7];
  const float* fe2_w = (const float*)d_in[8];
  const float* fe2_b = (const float*)d_in[9];
  const float* emb1  = (const float*)d_in[10];
  const float* emb2  = (const float*)d_in[11];
  const float* bb1_w = (const float*)d_in[12];
  const float* bb1_b = (const float*)d_in[13];
  const float* bb2_w = (const float*)d_in[14];
  const float* bb2_b = (const float*)d_in[15];
  const float* lobj_w = (const float*)d_in[16];
  const float* lobj_b = (const float*)d_in[17];
  const float* ledge_w = (const float*)d_in[18];
  const float* ledge_b = (const float*)d_in[19];
  const float* oqkv_w = (const float*)d_in[20];
  const float* oqkv_b = (const float*)d_in[21];
  const float* oout_w = (const float*)d_in[22];
  const float* oout_b = (const float*)d_in[23];
  const float* of1_w = (const float*)d_in[24];
  const float* of1_b = (const float*)d_in[25];
  const float* of2_w = (const float*)d_in[26];
  const float* of2_b = (const float*)d_in[27];
  const float* oln1_s = (const float*)d_in[28];
  const float* oln1_b = (const float*)d_in[29];
  const float* oln2_s = (const float*)d_in[30];
  const float* oln2_b = (const float*)d_in[31];
  const float* eqkv_w = (const float*)d_in[32];
  const float* eqkv_b = (const float*)d_in[33];
  const float* eout_w = (const float*)d_in[34];
  const float* eout_b = (const float*)d_in[35];
  const float* ef1_w = (const float*)d_in[36];
  const float* ef1_b = (const float*)d_in[37];
  const float* ef2_w = (const float*)d_in[38];
  const float* ef2_b = (const float*)d_in[39];
  const float* eln1_s = (const float*)d_in[40];
  const float* eln1_b = (const float*)d_in[41];
  const float* eln2_s = (const float*)d_in[42];
  const float* eln2_b = (const float*)d_in[43];
  const float* pcat_w = (const float*)d_in[44];
  const float* pcat_b = (const float*)d_in[45];
  const float* fuse_w = (const float*)d_in[46];
  const float* fuse_b = (const float*)d_in[47];
  const float* cpx_w  = (const float*)d_in[48];
  const float* cpx_b  = (const float*)d_in[49];
  const float* dpath_w = (const float*)d_in[50];
  const float* dpath_b = (const float*)d_in[51];

  char* wsb = (char*)d_ws;
  u16* feat_h  = (u16*)(wsb + OFF_FEAT);
  u16* fe1w_h  = (u16*)(wsb + OFF_FE1W);
  float* part  = (float*)(wsb + OFF_PART);
  u16* pair    = (u16*)(wsb + OFF_PAIR);
  u16* finalb  = (u16*)(wsb + OFF_FINAL);
  u16* obj_in  = (u16*)(wsb + OFF_OBJIN);
  u16* qkvh    = (u16*)(wsb + OFF_QKVH);
  float* x     = (float*)(wsb + OFF_X);
  u16* xh      = (u16*)(wsb + OFF_XH);
  u16* attn_h  = (u16*)(wsb + OFF_ATTN);
  float* res1  = (float*)(wsb + OFF_RES);
  u16* f_h     = (u16*)(wsb + OFF_FH);
  u16* edge_in = (u16*)(wsb + OFF_EDGE);

  size_t off = P_END;
  auto alloc = [&](size_t bytes) { char* p = wsb + off; off = (off + bytes + 255) & ~(size_t)255; return p; };
  u16* bf0h     = (u16*)alloc(2621440);
  u16* catw     = (u16*)alloc(313344);
  float* biasc  = (float*)alloc(256);
  float* gctx   = (float*)alloc(32768);
  float* gcproj = (float*)alloc(65536);
  float* binfo  = (float*)alloc(46080);
  float* pos1   = (float*)alloc(163840);
  float* pos2   = (float*)alloc(655360);
  float* fpart  = (float*)alloc(4194304);  // 4 * 4096 * 64 * 4

  // --- 1) converts for fe1 inputs (big GEMM keeps bf16 staging) ---
  {
    const int n4a = cN * cDF / 4;
    conv_kernel<<<(n4a + 255) / 256, 256, 0, stream>>>(features, feat_h, n4a);
    const int n4b = cREP * cDF / 4;
    conv_kernel<<<(n4b + 255) / 256, 256, 0, stream>>>(fe1_w, fe1w_h, n4b);
  }

  // --- 2) fe1 split-K=8 + reduce -> bf0h ---
  gemm_h<128, 128, true, false><<<dim3(8, 10, 8), 256, 0, stream>>>(
      feat_h, cDF, fe1w_h, cDF, cN, cREP, cDF / 8, part, cREP,
      nullptr, 0, nullptr, nullptr, 0, 0, 0);
  reduce8_kernel<<<(cN * cREP + 255) / 256, 256, 0, stream>>>(part, fe1_b, bf0h);

  // --- 3) box path + gathers into obj_in ---
  box_info_kernel<<<(cN + 255) / 256, 256, 0, stream>>>(boxes, binfo);
  gemm_nt<<<dim3(1, 20), 256, 0, stream>>>(binfo, 9, bb1_w, 9, pos1, 32, bb1_b, cN, 32, 9, 2);
  gemm_nt<<<dim3(2, 20), 256, 0, stream>>>(pos1, 32, bb2_w, 32, pos2, 128, bb2_b, cN, 128, 32, 2);
  conv2d_kernel<<<cN, 128, 0, stream>>>(pos2, 128, obj_in + 1280, 1408, 128);
  gather_emb_h<<<cN, 256, 0, stream>>>(emb1, labels, obj_in + 1024, 1408);

  // --- 4) fe2 -> obj_in[:, :1024] (W fp32 direct) ---
  g16<64, 64, true>(stream, bf0h, 1024, fe2_w, 1024, cN, cREP, cREP,
                    nullptr, 0, obj_in, 1408, fe2_b, nullptr, 0, 0, 1);

  // --- 5) obj_rep -> x, xh ---
  g16<64, 64, true>(stream, obj_in, 1408, lobj_w, 1408, cN, cHID, 1408,
                    x, 512, xh, 512, lobj_b, nullptr, 0, 0, 0);

  // --- 6) object encoder (final LN -> edge_in[:, :512]) ---
  run_encoder(stream, x, xh, qkvh, attn_h, res1, f_h,
              oqkv_w, oqkv_b, oout_w, oout_b, of1_w, of1_b, of2_w, of2_b,
              oln1_s, oln1_b, oln2_s, oln2_b, edge_in, 768);

  // --- 7) emb2 gather + pair gather ---
  gather_emb_h<<<cN, 256, 0, stream>>>(emb2, labels, edge_in + 512, 768);
  pair_gather_h<<<cR, 256, 0, stream>>>(edge_in, 768, relidx, pair);

  // --- 8) edge encoder -> gctx ---
  g16<64, 64, true>(stream, edge_in, 768, ledge_w, 768, cN, cHID, 768,
                    x, 512, xh, 512, ledge_b, nullptr, 0, 0, 0);
  run_encoder(stream, x, xh, qkvh, attn_h, res1, f_h,
              eqkv_w, eqkv_b, eout_w, eout_b, ef1_w, ef1_b, ef2_w, ef2_b,
              eln1_s, eln1_b, eln2_s, eln2_b, xh, 512);
  mean_kernel<<<cB, cHID, 0, stream>>>(x, gctx);

  // --- 9) gcproj = gctx @ fuse_w[:,1024:]^T + fuse_b (16x1024 fp32) ---
  gemm_nt<<<dim3(16, 1), 256, 0, stream>>>(gctx, 512, fuse_w + 1024, 1536, gcproj, 1024,
                                           fuse_b, cB, cREP, 512, 0);

  // --- 10) final feature block: [fuse-out | union | local] ---
  conv2d_kernel<<<cR, 256, 0, stream>>>(unionf, 1024, finalb + 1024, 3072, 1024);
  g16<128, 64, true>(stream, pair, 1024, pcat_w, 1024, cR, cREP, 1024,
                     nullptr, 0, finalb + 2048, 3072, pcat_b, nullptr, 0, 0, 0);
  g16<128, 64, true>(stream, finalb + 2048, 3072, fuse_w, 1536, cR, cREP, 1024,
                     nullptr, 0, finalb, 3072, nullptr, gcproj, 1024, 2, 1);

  // --- 11) rel_logits = final @ [cpx1|cpx2|dpath]^T + (cpx_b+dpath_b) ---
  conv2d_kernel<<<cRELC, 256, 0, stream>>>(cpx_w, 2048, catw, 3072, 2048);
  conv2d_kernel<<<cRELC, 256, 0, stream>>>(dpath_w, 1024, catw + 2048, 3072, 1024);
  addb_kernel<<<1, 64, 0, stream>>>(cpx_b, dpath_b, biasc, cRELC);
  gemm_h<64, 64, true, false><<<dim3(1, 64, 4), 256, 0, stream>>>(
      finalb, 3072, catw, 3072, cR, cRELC, 3072 / 4, fpart, 64,
      nullptr, 0, nullptr, nullptr, 0, 0, 0);
  freduce_kernel<<<(cR * cRELC + 255) / 256, 256, 0, stream>>>(fpart, biasc, (float*)d_out);
}

// Round 4
// 1008.341 us; speedup vs baseline: 1.7678x; 1.7678x over previous
//
#include <hip/hip_runtime.h>
#include <hip/hip_bf16.h>
#include <cstdint>

#define DEV_INLINE __device__ __forceinline__

using u16 = unsigned short;
typedef __attribute__((ext_vector_type(8))) short bf8_t;   // 8 x bf16 (4 VGPR)
typedef __attribute__((ext_vector_type(4))) float f32x4;

constexpr int cB = 16, cM = 80, cRPI = 256;
constexpr int cN = cB * cM;        // 1280
constexpr int cR = cB * cRPI;      // 4096
constexpr int cDF = 12544, cREP = 1024, cEMB = 256, cHID = 512, cNH = 8, cL = 4;
constexpr int cRELC = 51;

DEV_INLINE u16 f2bf(float x) { return __builtin_bit_cast(u16, __float2bfloat16(x)); }
DEV_INLINE float bf2f(u16 u) { return __bfloat162float(__builtin_bit_cast(__hip_bfloat16, u)); }

DEV_INLINE float wave_max(float v) {
#pragma unroll
  for (int o = 32; o; o >>= 1) v = fmaxf(v, __shfl_xor(v, o));
  return v;
}
DEV_INLINE float wave_sum(float v) {
#pragma unroll
  for (int o = 32; o; o >>= 1) v += __shfl_xor(v, o);
  return v;
}

// XCD-bijective remap (m204): each XCD gets a contiguous chunk of linear ids.
DEV_INLINE void xcd_remap(int& bx, int& by) {
  const int gx = gridDim.x;
  const int nwg = gx * gridDim.y;
  const int id = blockIdx.x + gx * blockIdx.y;
  const int q = nwg >> 3, r = nwg & 7;
  const int x = id & 7, k = id >> 3;
  const int idp = (x < r) ? x * (q + 1) + k : r * (q + 1) + (x - r) * q + k;
  bx = idp % gx;
  by = idp / gx;
}

// =====================================================================
// bf16 MFMA GEMM: C(MxN) = A(MxK bf16,row) @ W(NxK bf16,row)^T.
// 256 thr = 4 waves (2x2), 16x16x32 MFMA, BK=32, double-buffered LDS with
// prefetch-before-compute (one barrier per K-step). 16B-granule XOR swizzle
// (src-side pre-swizzle, linear LDS dest): granule g at row r holds global
// granule g^(r&3) -> frag read uses l4^(r&3). M must be multiple of BM.
// N ragged (B-row clamp + store guard). lda/ldb multiples of 8.
// SPLIT: blockIdx.z K-chunks, fp32 partials to outF + z*Mr*ldc.
// resmode: 0 none, 1 res[r*resld+c], 2 res[(r>>8)*resld+c] (row-broadcast).
// =====================================================================
template <int BM, int BN, bool SPLIT>
__global__ __launch_bounds__(256) void gemm_h(
    const u16* __restrict__ A, int lda,
    const u16* __restrict__ Bw, int ldb,
    int Mr, int Nr, int Klen,
    float* __restrict__ outF, int ldc,
    u16* __restrict__ outH, int ldh,
    const float* __restrict__ bias,
    const float* __restrict__ res, int resld, int resmode,
    int relu)
{
  constexpr int MF = BM / 32, NF = BN / 32;
  __shared__ u16 As[2][BM * 32];
  __shared__ u16 Bs[2][BN * 32];
  const int tid = threadIdx.x;
  const int wid = tid >> 6, lane = tid & 63;
  const int l15 = lane & 15, l4 = lane >> 4;
  int bx, by;
  xcd_remap(bx, by);
  const int bm = by * BM, bn = bx * BN;
  const int wr = wid >> 1, wc = wid & 1;
  const int kbase = SPLIT ? blockIdx.z * Klen : 0;

  f32x4 acc[MF][NF] = {};

  constexpr int AISS = (BM * 4) / 256;   // 16B chunks per thread for A tile
  constexpr int BISS = (BN * 4) / 256;

  auto stage = [&](int buf, int ks) {
    const int k0 = kbase + (ks << 5);
#pragma unroll
    for (int i = 0; i < AISS; ++i) {
      const int c = i * 256 + tid;
      const int row = c >> 2, seg = c & 3;
      const int sseg = seg ^ (row & 3);              // pre-swizzled source
      const u16* gp = A + (size_t)(bm + row) * lda + k0 + sseg * 8;
      __builtin_amdgcn_global_load_lds(
          (const __attribute__((address_space(1))) void*)gp,
          (__attribute__((address_space(3))) void*)((char*)As[buf] + (size_t)(i * 256 + wid * 64) * 16),
          16, 0, 0);
    }
#pragma unroll
    for (int i = 0; i < BISS; ++i) {
      const int c = i * 256 + tid;
      const int row = c >> 2, seg = c & 3;
      const int sseg = seg ^ (row & 3);
      int brow = bn + row; if (brow > Nr - 1) brow = Nr - 1;  // ragged-N clamp
      const u16* gp = Bw + (size_t)brow * ldb + k0 + sseg * 8;
      __builtin_amdgcn_global_load_lds(
          (const __attribute__((address_space(1))) void*)gp,
          (__attribute__((address_space(3))) void*)((char*)Bs[buf] + (size_t)(i * 256 + wid * 64) * 16),
          16, 0, 0);
    }
  };

  const int nk = Klen >> 5;
  stage(0, 0);
  __syncthreads();

  for (int ks = 0; ks < nk; ++ks) {
    const int cur = ks & 1;
    if (ks + 1 < nk) stage(cur ^ 1, ks + 1);   // prefetch overlaps compute

    bf8_t af[MF], bfr[NF];
#pragma unroll
    for (int m = 0; m < MF; ++m) {
      const int r = wr * (BM / 2) + m * 16 + l15;
      const int g = l4 ^ (r & 3);
      af[m] = *(const bf8_t*)&As[cur][r * 32 + g * 8];
    }
#pragma unroll
    for (int n = 0; n < NF; ++n) {
      const int r = wc * (BN / 2) + n * 16 + l15;
      const int g = l4 ^ (r & 3);
      bfr[n] = *(const bf8_t*)&Bs[cur][r * 32 + g * 8];
    }
#pragma unroll
    for (int m = 0; m < MF; ++m)
#pragma unroll
      for (int n = 0; n < NF; ++n)
        acc[m][n] = __builtin_amdgcn_mfma_f32_16x16x32_bf16(af[m], bfr[n], acc[m][n], 0, 0, 0);
    __syncthreads();   // drains prefetch + guards buffer reuse
  }

  if (SPLIT) {
    float* po = outF + (size_t)blockIdx.z * Mr * ldc;
#pragma unroll
    for (int m = 0; m < MF; ++m)
#pragma unroll
      for (int n = 0; n < NF; ++n) {
        const int ccol = bn + wc * (BN / 2) + n * 16 + l15;
        if (ccol >= Nr) continue;
#pragma unroll
        for (int g = 0; g < 4; ++g) {
          const int r = bm + wr * (BM / 2) + m * 16 + l4 * 4 + g;
          po[(size_t)r * ldc + ccol] = acc[m][n][g];
        }
      }
  } else {
#pragma unroll
    for (int m = 0; m < MF; ++m)
#pragma unroll
      for (int n = 0; n < NF; ++n) {
        const int ccol = bn + wc * (BN / 2) + n * 16 + l15;
        if (ccol >= Nr) continue;
        const float bv = bias ? bias[ccol] : 0.f;
#pragma unroll
        for (int g = 0; g < 4; ++g) {
          const int r = bm + wr * (BM / 2) + m * 16 + l4 * 4 + g;
          float v = acc[m][n][g] + bv;
          if (resmode == 1) v += res[(size_t)r * resld + ccol];
          else if (resmode == 2) v += res[(size_t)(r >> 8) * resld + ccol];
          if (relu) v = fmaxf(v, 0.f);
          if (outF) outF[(size_t)r * ldc + ccol] = v;
          if (outH) outH[(size_t)r * ldh + ccol] = f2bf(v);
        }
      }
  }
}

template <int BM, int BN>
static void g16(hipStream_t s, const u16* A, int lda, const u16* W, int ldb,
                int M, int N, int K, float* outF, int ldc, u16* outH, int ldh,
                const float* bias, const float* res, int resld, int resmode, int relu) {
  dim3 g((N + BN - 1) / BN, M / BM);
  gemm_h<BM, BN, false><<<g, 256, 0, s>>>(A, lda, W, ldb, M, N, K, outF, ldc, outH, ldh,
                                          bias, res, resld, resmode, relu);
}

// ---------- fp32 fallback GEMM (tiny shapes) ----------
__global__ __launch_bounds__(256) void gemm_nt(
    const float* __restrict__ A, int lda,
    const float* __restrict__ Bw, int ldb,
    float* __restrict__ C, int ldc,
    const float* __restrict__ bias,
    int Mr, int Nr, int Kr, int flags)
{
  __shared__ float As[16][68];
  __shared__ float Bs[16][68];
  const int tid = threadIdx.x;
  const int tx = tid & 15, ty = tid >> 4;
  const int bm = blockIdx.y * 64, bn = blockIdx.x * 64;
  const int lr = tid >> 2;
  const int lk = (tid & 3) * 4;

  float acc[4][4];
#pragma unroll
  for (int i = 0; i < 4; ++i)
#pragma unroll
    for (int j = 0; j < 4; ++j) acc[i][j] = 0.f;

  for (int k0 = 0; k0 < Kr; k0 += 16) {
    const int ar = bm + lr, br = bn + lr;
#pragma unroll
    for (int j = 0; j < 4; ++j) {
      const int kk = k0 + lk + j;
      float va = 0.f, vb = 0.f;
      if (kk < Kr) {
        if (ar < Mr) va = A[(size_t)ar * lda + kk];
        if (br < Nr) vb = Bw[(size_t)br * ldb + kk];
      }
      As[lk + j][lr] = va;
      Bs[lk + j][lr] = vb;
    }
    __syncthreads();
#pragma unroll
    for (int kk = 0; kk < 16; ++kk) {
      const float a0 = As[kk][ty * 4 + 0], a1 = As[kk][ty * 4 + 1],
                  a2 = As[kk][ty * 4 + 2], a3 = As[kk][ty * 4 + 3];
      const float b0 = Bs[kk][tx * 4 + 0], b1 = Bs[kk][tx * 4 + 1],
                  b2 = Bs[kk][tx * 4 + 2], b3 = Bs[kk][tx * 4 + 3];
      acc[0][0] += a0 * b0; acc[0][1] += a0 * b1; acc[0][2] += a0 * b2; acc[0][3] += a0 * b3;
      acc[1][0] += a1 * b0; acc[1][1] += a1 * b1; acc[1][2] += a1 * b2; acc[1][3] += a1 * b3;
      acc[2][0] += a2 * b0; acc[2][1] += a2 * b1; acc[2][2] += a2 * b2; acc[2][3] += a2 * b3;
      acc[3][0] += a3 * b0; acc[3][1] += a3 * b1; acc[3][2] += a3 * b2; acc[3][3] += a3 * b3;
    }
    __syncthreads();
  }
#pragma unroll
  for (int i = 0; i < 4; ++i) {
    const int r = bm + ty * 4 + i;
    if (r >= Mr) continue;
#pragma unroll
    for (int j = 0; j < 4; ++j) {
      const int c = bn + tx * 4 + j;
      if (c >= Nr) continue;
      float v = acc[i][j];
      if (bias) v += bias[c];
      if (flags & 2) v = fmaxf(v, 0.f);
      C[(size_t)r * ldc + c] = v;
    }
  }
}

// ---------- small kernels ----------
__global__ void conv_kernel(const float* __restrict__ s, u16* __restrict__ d, int n4) {
  const int i = blockIdx.x * 256 + threadIdx.x;
  if (i >= n4) return;
  const float4 v = ((const float4*)s)[i];
  ushort4 o;
  o.x = f2bf(v.x); o.y = f2bf(v.y); o.z = f2bf(v.z); o.w = f2bf(v.w);
  ((ushort4*)d)[i] = o;
}

__global__ void conv2d_kernel(const float* __restrict__ src, int slda,
                              u16* __restrict__ dst, int dld, int cols) {
  const int r = blockIdx.x;
  for (int c = threadIdx.x; c < cols; c += blockDim.x)
    dst[(size_t)r * dld + c] = f2bf(src[(size_t)r * slda + c]);
}

__global__ void addb_kernel(const float* a, const float* b, float* o, int n) {
  const int i = threadIdx.x;
  if (i < n) o[i] = a[i] + b[i];
}

__global__ void box_info_kernel(const float* __restrict__ boxes, float* __restrict__ bi) {
  const int i = blockIdx.x * blockDim.x + threadIdx.x;
  if (i >= cN) return;
  const float x1 = boxes[i * 4 + 0], y1 = boxes[i * 4 + 1];
  const float x2 = boxes[i * 4 + 2], y2 = boxes[i * 4 + 3];
  const float w = x2 - x1 + 1.f, h = y2 - y1 + 1.f;
  const float cx = x1 + 0.5f * w, cy = y1 + 0.5f * h;
  float* o = bi + (size_t)i * 9;
  o[0] = w / 800.f;  o[1] = h / 600.f;
  o[2] = cx / 800.f; o[3] = cy / 600.f;
  o[4] = x1 / 800.f; o[5] = y1 / 600.f;
  o[6] = x2 / 800.f; o[7] = y2 / 600.f;
  o[8] = (w * h) / (800.f * 600.f);
}

__global__ void gather_emb_h(const float* __restrict__ emb, const int* __restrict__ labels,
                             u16* __restrict__ dst, int dld) {
  const int i = blockIdx.x;
  const int l = labels[i];
  const float* s = emb + (size_t)l * cEMB;
  for (int c = threadIdx.x; c < cEMB; c += blockDim.x)
    dst[(size_t)i * dld + c] = f2bf(s[c]);
}

// fused attention per (b,h): qkv bf16 in, bf16 out
__global__ __launch_bounds__(256) void attn_kernel(const u16* __restrict__ qkv,
                                                   u16* __restrict__ o) {
  __shared__ float Ks[80][65];
  __shared__ float Vs[80][65];
  const int bh = blockIdx.x;
  const int b = bh >> 3, h = bh & 7;
  const int tid = threadIdx.x;
  const u16* base = qkv + (size_t)(b * cM) * 1536 + h * 64;

  for (int e = tid; e < 80 * 64; e += 256) {
    const int r = e >> 6, d = e & 63;
    Ks[r][d] = bf2f(base[(size_t)r * 1536 + 512 + d]);
    Vs[r][d] = bf2f(base[(size_t)r * 1536 + 1024 + d]);
  }
  __syncthreads();

  const int wave = tid >> 6, lane = tid & 63;
  const int r0 = blockIdx.y * 16;
  for (int r = r0 + wave; r < r0 + 16; r += 4) {
    const float qd = bf2f(base[(size_t)r * 1536 + lane]);
    const int c2 = 64 + lane;
    const int c2c = (c2 < 80) ? c2 : 0;
    float s0 = 0.f, s1 = 0.f;
#pragma unroll 8
    for (int d = 0; d < 64; ++d) {
      const float qv = __shfl(qd, d);
      s0 += qv * Ks[lane][d];
      s1 += qv * Ks[c2c][d];
    }
    s0 *= 0.125f;
    s1 = (c2 < 80) ? s1 * 0.125f : -1e30f;
    const float mx = wave_max(fmaxf(s0, s1));
    const float p0 = __expf(s0 - mx);
    const float p1 = (c2 < 80) ? __expf(s1 - mx) : 0.f;
    const float ssum = wave_sum(p0 + p1);

    float od = 0.f;
#pragma unroll 8
    for (int c = 0; c < 64; ++c) od += __shfl(p0, c) * Vs[c][lane];
#pragma unroll
    for (int c = 0; c < 16; ++c) od += __shfl(p1, c) * Vs[64 + c][lane];
    od /= ssum;
    o[(size_t)(b * cM + r) * cHID + h * 64 + lane] = f2bf(od);
  }
}

// ---------- LayerNorm over 512: 4 rows/block, 1 wave/row ----------
__global__ __launch_bounds__(256) void ln_kernel(
    const float* __restrict__ in, float* __restrict__ outF,
    u16* __restrict__ outH, int ldh,
    const float* __restrict__ g, const float* __restrict__ bta) {
  const int row = blockIdx.x * 4 + (threadIdx.x >> 6);
  const int lane = threadIdx.x & 63;
  const float* x = in + (size_t)row * cHID;
  float v[8];
  float s = 0.f;
#pragma unroll
  for (int i = 0; i < 8; ++i) { v[i] = x[lane + i * 64]; s += v[i]; }
  s = wave_sum(s);
  const float mean = s * (1.f / 512.f);
  float vs = 0.f;
#pragma unroll
  for (int i = 0; i < 8; ++i) { const float d = v[i] - mean; vs += d * d; }
  vs = wave_sum(vs);
  const float inv = rsqrtf(vs * (1.f / 512.f) + 1e-5f);
#pragma unroll
  for (int i = 0; i < 8; ++i) {
    const int c = lane + i * 64;
    const float y = (v[i] - mean) * inv * g[c] + bta[c];
    outF[(size_t)row * cHID + c] = y;
    outH[(size_t)row * ldh + c] = f2bf(y);
  }
}

__global__ void mean_kernel(const float* __restrict__ x, float* __restrict__ gctx) {
  const int b = blockIdx.x;
  const int c = threadIdx.x;  // 512
  float s = 0.f;
  for (int m = 0; m < cM; ++m) s += x[(size_t)(b * cM + m) * cHID + c];
  gctx[(size_t)b * cHID + c] = s * (1.f / 80.f);
}

__global__ void pair_gather_h(const u16* __restrict__ obj, int old, const int* __restrict__ idx,
                              u16* __restrict__ pair) {
  const int r = blockIdx.x;
  const int b = r >> 8, rr = r & 255;
  const int i0 = idx[(size_t)(b * cRPI + rr) * 2 + 0];
  const int i1 = idx[(size_t)(b * cRPI + rr) * 2 + 1];
  const u16* hsrc = obj + (size_t)(b * cM + i0) * old;
  const u16* tsrc = obj + (size_t)(b * cM + i1) * old;
  u16* p = pair + (size_t)r * 1024;
  for (int c = threadIdx.x; c < cHID; c += blockDim.x) {
    p[c] = hsrc[c];
    p[cHID + c] = tsrc[c];
  }
}

// fe1 split-K=8 reduce: +bias, relu -> bf16
__global__ void reduce8_kernel(const float* __restrict__ p, const float* __restrict__ bias,
                               u16* __restrict__ outH) {
  const int idx = blockIdx.x * 256 + threadIdx.x;
  constexpr int total = cN * cREP;
  if (idx >= total) return;
  float v = bias[idx & 1023];
#pragma unroll
  for (int z = 0; z < 8; ++z) v += p[(size_t)z * total + idx];
  outH[idx] = f2bf(fmaxf(v, 0.f));
}

// final split-K=4 reduce: +combined bias -> fp32 d_out
__global__ void freduce_kernel(const float* __restrict__ p, const float* __restrict__ biasc,
                               float* __restrict__ out) {
  const int idx = blockIdx.x * 256 + threadIdx.x;
  if (idx >= cR * cRELC) return;
  const int r = idx / cRELC, c = idx - r * cRELC;
  float v = biasc[c];
#pragma unroll
  for (int z = 0; z < 4; ++z) v += p[(size_t)z * cR * 64 + (size_t)r * 64 + c];
  out[idx] = v;
}

// ---------- encoder: 7 dispatches per layer (bf16 weights) ----------
static void run_encoder(hipStream_t s, float* x, u16* xh, u16* qkvh, u16* attn_h,
                        float* res1, u16* f_h,
                        const u16* qkvw, const float* qkvb,
                        const u16* outw, const float* outb,
                        const u16* f1w, const float* f1b,
                        const u16* f2w, const float* f2b,
                        const float* ln1s, const float* ln1b,
                        const float* ln2s, const float* ln2b,
                        u16* last_bf, int last_ld) {
  for (int l = 0; l < cL; ++l) {
    g16<64, 64>(s, xh, 512, qkvw + (size_t)l * 1536 * 512, 512, cN, 1536, 512,
                nullptr, 0, qkvh, 1536, qkvb + l * 1536, nullptr, 0, 0, 0);
    attn_kernel<<<dim3(cB * cNH, 5), 256, 0, s>>>(qkvh, attn_h);
    g16<64, 64>(s, attn_h, 512, outw + (size_t)l * 512 * 512, 512, cN, 512, 512,
                res1, 512, nullptr, 0, outb + l * 512, x, 512, 1, 0);
    ln_kernel<<<cN / 4, 256, 0, s>>>(res1, x, xh, 512, ln1s + l * 512, ln1b + l * 512);
    g16<64, 64>(s, xh, 512, f1w + (size_t)l * 512 * 512, 512, cN, 512, 512,
                nullptr, 0, f_h, 512, f1b + l * 512, nullptr, 0, 0, 1);
    g16<64, 64>(s, f_h, 512, f2w + (size_t)l * 512 * 512, 512, cN, 512, 512,
                res1, 512, nullptr, 0, f2b + l * 512, x, 512, 1, 0);
    const bool last = (l == cL - 1);
    ln_kernel<<<cN / 4, 256, 0, s>>>(res1, x, last ? last_bf : xh, last ? last_ld : 512,
                                     ln2s + l * 512, ln2b + l * 512);
  }
}

// ===== workspace layout (bytes) =====
// phase1: feat_h | fe1w_h | part — all dead after reduce8
// phase2 overlays 0..52.3M: pair|finalb|obj_in|qkvh|x|xh|attn_h|res1|f_h|edge_in
constexpr size_t OFF_FEAT  = 0;
constexpr size_t OFF_FE1W  = 32112640;
constexpr size_t OFF_PART  = 57802752;   // 8*1280*1024*4 = 41,943,040
constexpr size_t P_END     = 99745792;
constexpr size_t OFF_PAIR  = 0;          //  8,388,608
constexpr size_t OFF_FINAL = 8388608;    // 25,165,824
constexpr size_t OFF_OBJIN = 33554432;   //  3,604,480
constexpr size_t OFF_QKVH  = 37158912;   //  3,932,160
constexpr size_t OFF_X     = 41091072;   //  2,621,440
constexpr size_t OFF_XH    = 43712512;   //  1,310,720
constexpr size_t OFF_ATTN  = 45023232;   //  1,310,720
constexpr size_t OFF_RES   = 46333952;   //  2,621,440
constexpr size_t OFF_FH    = 48955392;   //  1,310,720
constexpr size_t OFF_EDGE  = 50266112;   //  1,966,080 -> ends 52,232,192

extern "C" void kernel_launch(void* const* d_in, const int* in_sizes, int n_in,
                              void* d_out, int out_size, void* d_ws, size_t ws_size,
                              hipStream_t stream) {
  (void)in_sizes; (void)n_in; (void)out_size; (void)ws_size;

  const float* features = (const float*)d_in[0];
  const float* unionf   = (const float*)d_in[1];
  const float* boxes    = (const float*)d_in[2];
  const int*   labels   = (const int*)d_in[4];
  const int*   relidx   = (const int*)d_in[5];
  const float* fe1_w = (const float*)d_in[6];
  const float* fe1_b = (const float*)d_in[7];
  const float* fe2_w = (const float*)d_in[8];
  const float* fe2_b = (const float*)d_in[9];
  const float* emb1  = (const float*)d_in[10];
  const float* emb2  = (const float*)d_in[11];
  const float* bb1_w = (const float*)d_in[12];
  const float* bb1_b = (const float*)d_in[13];
  const float* bb2_w = (const float*)d_in[14];
  const float* bb2_b = (const float*)d_in[15];
  const float* lobj_w = (const float*)d_in[16];
  const float* lobj_b = (const float*)d_in[17];
  const float* ledge_w = (const float*)d_in[18];
  const float* ledge_b = (const float*)d_in[19];
  const float* oqkv_w = (const float*)d_in[20];
  const float* oqkv_b = (const float*)d_in[21];
  const float* oout_w = (const float*)d_in[22];
  const float* oout_b = (const float*)d_in[23];
  const float* of1_w = (const float*)d_in[24];
  const float* of1_b = (const float*)d_in[25];
  const float* of2_w = (const float*)d_in[26];
  const float* of2_b = (const float*)d_in[27];
  const float* oln1_s = (const float*)d_in[28];
  const float* oln1_b = (const float*)d_in[29];
  const float* oln2_s = (const float*)d_in[30];
  const float* oln2_b = (const float*)d_in[31];
  const float* eqkv_w = (const float*)d_in[32];
  const float* eqkv_b = (const float*)d_in[33];
  const float* eout_w = (const float*)d_in[34];
  const float* eout_b = (const float*)d_in[35];
  const float* ef1_w = (const float*)d_in[36];
  const float* ef1_b = (const float*)d_in[37];
  const float* ef2_w = (const float*)d_in[38];
  const float* ef2_b = (const float*)d_in[39];
  const float* eln1_s = (const float*)d_in[40];
  const float* eln1_b = (const float*)d_in[41];
  const float* eln2_s = (const float*)d_in[42];
  const float* eln2_b = (const float*)d_in[43];
  const float* pcat_w = (const float*)d_in[44];
  const float* pcat_b = (const float*)d_in[45];
  const float* fuse_w = (const float*)d_in[46];
  const float* fuse_b = (const float*)d_in[47];
  const float* cpx_w  = (const float*)d_in[48];
  const float* cpx_b  = (const float*)d_in[49];
  const float* dpath_w = (const float*)d_in[50];
  const float* dpath_b = (const float*)d_in[51];

  char* wsb = (char*)d_ws;
  u16* feat_h  = (u16*)(wsb + OFF_FEAT);
  u16* fe1w_h  = (u16*)(wsb + OFF_FE1W);
  float* part  = (float*)(wsb + OFF_PART);
  u16* pair    = (u16*)(wsb + OFF_PAIR);
  u16* finalb  = (u16*)(wsb + OFF_FINAL);
  u16* obj_in  = (u16*)(wsb + OFF_OBJIN);
  u16* qkvh    = (u16*)(wsb + OFF_QKVH);
  float* x     = (float*)(wsb + OFF_X);
  u16* xh      = (u16*)(wsb + OFF_XH);
  u16* attn_h  = (u16*)(wsb + OFF_ATTN);
  float* res1  = (float*)(wsb + OFF_RES);
  u16* f_h     = (u16*)(wsb + OFF_FH);
  u16* edge_in = (u16*)(wsb + OFF_EDGE);

  size_t off = P_END;
  auto alloc = [&](size_t bytes) { char* p = wsb + off; off = (off + bytes + 255) & ~(size_t)255; return p; };
  u16* fe2w_h   = (u16*)alloc(2097152);
  u16* lobjw_h  = (u16*)alloc(1441792);
  u16* ledgew_h = (u16*)alloc(786432);
  u16* oqkvw_h  = (u16*)alloc(6291456);
  u16* ooutw_h  = (u16*)alloc(2097152);
  u16* of1w_h   = (u16*)alloc(2097152);
  u16* of2w_h   = (u16*)alloc(2097152);
  u16* eqkvw_h  = (u16*)alloc(6291456);
  u16* eoutw_h  = (u16*)alloc(2097152);
  u16* ef1w_h   = (u16*)alloc(2097152);
  u16* ef2w_h   = (u16*)alloc(2097152);
  u16* pcatw_h  = (u16*)alloc(2097152);
  u16* fusew_h  = (u16*)alloc(3145728);
  u16* catw     = (u16*)alloc(313344);
  float* biasc  = (float*)alloc(256);
  u16* bf0h     = (u16*)alloc(2621440);
  float* gctx   = (float*)alloc(131072);    // 64 rows x 512 (rows 16+ scratch)
  u16* gctx_h   = (u16*)alloc(65536);       // 64 x 512 bf16
  float* gcproj = (float*)alloc(262144);    // 64 x 1024 (rows 16+ scratch)
  float* binfo  = (float*)alloc(46080);
  float* pos1   = (float*)alloc(163840);
  float* pos2   = (float*)alloc(655360);
  float* fpart  = (float*)alloc(4194304);   // 4 * 4096 * 64 * 4

  auto conv = [&](const float* s, u16* d, size_t n) {
    const int n4 = (int)(n / 4);
    conv_kernel<<<(n4 + 255) / 256, 256, 0, stream>>>(s, d, n4);
  };

  // --- 1) converts ---
  conv(features, feat_h, (size_t)cN * cDF);
  conv(fe1_w, fe1w_h, (size_t)cREP * cDF);
  conv(fe2_w, fe2w_h, (size_t)cREP * cREP);
  conv(lobj_w, lobjw_h, (size_t)cHID * 1408);
  conv(ledge_w, ledgew_h, (size_t)cHID * 768);
  conv(oqkv_w, oqkvw_h, (size_t)cL * 1536 * 512);
  conv(oout_w, ooutw_h, (size_t)cL * 512 * 512);
  conv(of1_w, of1w_h, (size_t)cL * 512 * 512);
  conv(of2_w, of2w_h, (size_t)cL * 512 * 512);
  conv(eqkv_w, eqkvw_h, (size_t)cL * 1536 * 512);
  conv(eout_w, eoutw_h, (size_t)cL * 512 * 512);
  conv(ef1_w, ef1w_h, (size_t)cL * 512 * 512);
  conv(ef2_w, ef2w_h, (size_t)cL * 512 * 512);
  conv(pcat_w, pcatw_h, (size_t)cREP * 1024);
  conv(fuse_w, fusew_h, (size_t)cREP * 1536);
  conv2d_kernel<<<cRELC, 256, 0, stream>>>(cpx_w, 2048, catw, 3072, 2048);
  conv2d_kernel<<<cRELC, 256, 0, stream>>>(dpath_w, 1024, catw + 2048, 3072, 1024);
  addb_kernel<<<1, 64, 0, stream>>>(cpx_b, dpath_b, biasc, cRELC);

  // --- 2) fe1 split-K=8 + reduce -> bf0h ---
  gemm_h<128, 128, true><<<dim3(8, 10, 8), 256, 0, stream>>>(
      feat_h, cDF, fe1w_h, cDF, cN, cREP, cDF / 8, part, cREP,
      nullptr, 0, nullptr, nullptr, 0, 0, 0);
  reduce8_kernel<<<(cN * cREP + 255) / 256, 256, 0, stream>>>(part, fe1_b, bf0h);

  // --- 3) box path + gathers into obj_in ---
  box_info_kernel<<<(cN + 255) / 256, 256, 0, stream>>>(boxes, binfo);
  gemm_nt<<<dim3(1, 20), 256, 0, stream>>>(binfo, 9, bb1_w, 9, pos1, 32, bb1_b, cN, 32, 9, 2);
  gemm_nt<<<dim3(2, 20), 256, 0, stream>>>(pos1, 32, bb2_w, 32, pos2, 128, bb2_b, cN, 128, 32, 2);
  conv2d_kernel<<<cN, 128, 0, stream>>>(pos2, 128, obj_in + 1280, 1408, 128);
  gather_emb_h<<<cN, 256, 0, stream>>>(emb1, labels, obj_in + 1024, 1408);

  // --- 4) fe2 -> obj_in[:, :1024] ---
  g16<64, 64>(stream, bf0h, 1024, fe2w_h, 1024, cN, cREP, cREP,
              nullptr, 0, obj_in, 1408, fe2_b, nullptr, 0, 0, 1);

  // --- 5) obj_rep -> x, xh ---
  g16<64, 64>(stream, obj_in, 1408, lobjw_h, 1408, cN, cHID, 1408,
              x, 512, xh, 512, lobj_b, nullptr, 0, 0, 0);

  // --- 6) object encoder (final LN -> edge_in[:, :512]) ---
  run_encoder(stream, x, xh, qkvh, attn_h, res1, f_h,
              oqkvw_h, oqkv_b, ooutw_h, oout_b, of1w_h, of1_b, of2w_h, of2_b,
              oln1_s, oln1_b, oln2_s, oln2_b, edge_in, 768);

  // --- 7) emb2 gather + pair gather ---
  gather_emb_h<<<cN, 256, 0, stream>>>(emb2, labels, edge_in + 512, 768);
  pair_gather_h<<<cR, 256, 0, stream>>>(edge_in, 768, relidx, pair);

  // --- 8) edge encoder -> gctx ---
  g16<64, 64>(stream, edge_in, 768, ledgew_h, 768, cN, cHID, 768,
              x, 512, xh, 512, ledge_b, nullptr, 0, 0, 0);
  run_encoder(stream, x, xh, qkvh, attn_h, res1, f_h,
              eqkvw_h, eqkv_b, eoutw_h, eout_b, ef1w_h, ef1_b, ef2w_h, ef2_b,
              eln1_s, eln1_b, eln2_s, eln2_b, xh, 512);
  mean_kernel<<<cB, cHID, 0, stream>>>(x, gctx);

  // --- 9) gcproj = gctx @ fuse_w[:,1024:]^T + fuse_b  (M=64, rows 16+ scratch) ---
  conv2d_kernel<<<16, 256, 0, stream>>>(gctx, 512, gctx_h, 512, 512);
  g16<64, 64>(stream, gctx_h, 512, fusew_h + 1024, 1536, 64, cREP, 512,
              gcproj, 1024, nullptr, 0, fuse_b, nullptr, 0, 0, 0);

  // --- 10) final feature block: [fuse-out | union | local] ---
  conv2d_kernel<<<cR, 256, 0, stream>>>(unionf, 1024, finalb + 1024, 3072, 1024);
  g16<128, 64>(stream, pair, 1024, pcatw_h, 1024, cR, cREP, 1024,
               nullptr, 0, finalb + 2048, 3072, pcat_b, nullptr, 0, 0, 0);
  g16<128, 64>(stream, finalb + 2048, 3072, fusew_h, 1536, cR, cREP, 1024,
               nullptr, 0, finalb, 3072, nullptr, gcproj, 1024, 2, 1);

  // --- 11) rel_logits = final @ [cpx1|cpx2|dpath]^T + (cpx_b+dpath_b) ---
  gemm_h<64, 64, true><<<dim3(1, 64, 4), 256, 0, stream>>>(
      finalb, 3072, catw, 3072, cR, cRELC, 3072 / 4, fpart, 64,
      nullptr, 0, nullptr, nullptr, 0, 0, 0);
  freduce_kernel<<<(cR * cRELC + 255) / 256, 256, 0, stream>>>(fpart, biasc, (float*)d_out);
}